// Round 5
// baseline (207.967 us; speedup 1.0000x reference)
//
#include <hip/hip_runtime.h>

#define N_COLS 24576
#define KSEL 64
#define TPB 256
#define F4T (N_COLS / 4 / TPB)   // 24 float4 per thread (select kernel)
#define CAP 512
#define NBINS 2048
#define PRE_F 2.4f               // static prefilter; 64th-largest of N(0,1) row ~2.79±0.04

#define FILL_BLOCKS 2048
#define TOTAL_F4 (4096 * (N_COLS / 4))          // 25165824
#define FILL_ITERS (TOTAL_F4 / (FILL_BLOCKS * TPB))  // 48

__device__ __forceinline__ unsigned toSortable(float x) {
    unsigned u = __float_as_uint(x);
    return (u & 0x80000000u) ? ~u : (u | 0x80000000u);
}
__device__ __forceinline__ float fromSortable(unsigned s) {
    unsigned u = (s & 0x80000000u) ? (s & 0x7FFFFFFFu) : ~s;
    return __uint_as_float(u);
}

// ---------------- kernel A: pure zero-fill (write stream) ----------------
extern "C" __global__ void __launch_bounds__(TPB, 8)
fill_zero_kernel(float4* __restrict__ out) {
    const float4 z4 = {0.0f, 0.0f, 0.0f, 0.0f};
    size_t base = (size_t)blockIdx.x * TPB + threadIdx.x;
    #pragma unroll 8
    for (int j = 0; j < FILL_ITERS; ++j)
        out[base + (size_t)j * (FILL_BLOCKS * TPB)] = z4;
}

// ------------- kernel B: pure read + select + sparse scatter -------------
extern "C" __global__ void __launch_bounds__(TPB, 8)
topk_select_kernel(const float* __restrict__ x, float* __restrict__ out) {
    __shared__ unsigned long long cand[CAP];   // key = (sortable<<15) | (24575-idx)
    __shared__ unsigned hist[NBINS];           // fallback only
    __shared__ int cand_cnt;
    __shared__ int sh_b1, sh_g;

    const int tid = threadIdx.x;
    const int row = blockIdx.x;
    const float4* __restrict__ xr = (const float4*)(x + (size_t)row * N_COLS);

    if (tid == 0) cand_cnt = 0;
    __syncthreads();

    // ---- pass 1: pure read stream, collect rare candidates ----
    #pragma unroll 8
    for (int j = 0; j < F4T; ++j) {
        int f = j * TPB + tid;
        float4 v = xr[f];

        #define PREF(comp, e)                                                     \
        if (v.comp > PRE_F) {                                                     \
            int p = atomicAdd(&cand_cnt, 1);                                      \
            if (p < CAP) {                                                        \
                unsigned s = toSortable(v.comp);                                  \
                cand[p] = ((unsigned long long)s << 15) |                         \
                          (unsigned long long)(24575 - (f * 4 + e));              \
            }                                                                     \
        }
        PREF(x, 0) PREF(y, 1) PREF(z, 2) PREF(w, 3)
        #undef PREF
    }
    __syncthreads();   // candidate list complete

    int C = cand_cnt;
    if (C >= KSEL && C <= CAP) {
        // ---- fast exact path: rank-select top-64 among candidates ----
        // Everything excluded is <= PRE_F < every candidate, so top-64 of
        // candidates == top-64 of the row. Tie-break: (value desc, index asc).
        for (int i = tid; i < C; i += TPB) {
            unsigned long long ki = cand[i];
            int rank = 0;
            for (int j = 0; j < C; ++j)
                rank += (cand[j] > ki) ? 1 : 0;   // broadcast LDS read
            if (rank < KSEL) {
                int idx = 24575 - (int)(ki & 0x7FFFULL);
                float v = fromSortable((unsigned)(ki >> 15));
                out[(size_t)row * N_COLS + idx] = v > 0.0f ? v : 0.0f;
            }
        }
        return;
    }

    // ---- fallback: exact histogram select (not taken for N(0,1) input) ----
    for (int i = tid; i < NBINS; i += TPB) hist[i] = 0u;
    if (tid == 0) cand_cnt = 0;
    __syncthreads();

    for (int j = 0; j < F4T; ++j) {
        int f = j * TPB + tid;
        float4 v = xr[f];
        atomicAdd(&hist[toSortable(v.x) >> 21], 1u);
        atomicAdd(&hist[toSortable(v.y) >> 21], 1u);
        atomicAdd(&hist[toSortable(v.z) >> 21], 1u);
        atomicAdd(&hist[toSortable(v.w) >> 21], 1u);
    }
    __syncthreads();

    if (tid < 64) {
        unsigned running = 0;
        for (int c = NBINS / 64 - 1; c >= 0; --c) {
            int bin = c * 64 + tid;
            unsigned cnt = hist[bin];
            unsigned incl = cnt;
            #pragma unroll
            for (int d = 1; d < 64; d <<= 1) {
                unsigned o = __shfl_up(incl, d, 64);
                if (tid >= d) incl += o;
            }
            unsigned total = __shfl(incl, 63, 64);
            unsigned gt = running + (total - incl);
            bool cond = (gt < KSEL) && (gt + cnt >= KSEL);
            unsigned long long m = __ballot(cond);
            if (m != 0ULL) {
                if (cond) { sh_b1 = bin; sh_g = (int)gt; }
                break;
            }
            running += total;
        }
    }
    __syncthreads();

    const int b1 = sh_b1;
    const int g  = sh_g;

    for (int j = 0; j < F4T; ++j) {
        int f = j * TPB + tid;
        float4 v = xr[f];
        #define FPROC(comp, e)                                                    \
        {                                                                         \
            unsigned s = toSortable(v.comp);                                      \
            int b = (int)(s >> 21);                                               \
            if (b > b1) {                                                         \
                float vv = v.comp > 0.0f ? v.comp : 0.0f;                         \
                out[(size_t)row * N_COLS + f * 4 + e] = vv;                       \
            } else if (b == b1) {                                                 \
                int p = atomicAdd(&cand_cnt, 1);                                  \
                if (p < CAP) {                                                    \
                    cand[p] = ((unsigned long long)s << 15) |                     \
                              (unsigned long long)(24575 - (f * 4 + e));          \
                }                                                                 \
            }                                                                     \
        }
        FPROC(x, 0) FPROC(y, 1) FPROC(z, 2) FPROC(w, 3)
        #undef FPROC
    }
    __syncthreads();

    int C2 = cand_cnt;
    if (C2 > CAP) C2 = CAP;
    const int k1 = KSEL - g;
    for (int i = tid; i < C2; i += TPB) {
        unsigned long long ki = cand[i];
        int rank = 0;
        for (int j = 0; j < C2; ++j)
            rank += (cand[j] > ki) ? 1 : 0;
        if (rank < k1) {
            int idx = 24575 - (int)(ki & 0x7FFFULL);
            float v = fromSortable((unsigned)(ki >> 15));
            out[(size_t)row * N_COLS + idx] = v > 0.0f ? v : 0.0f;
        }
    }
}

extern "C" void kernel_launch(void* const* d_in, const int* in_sizes, int n_in,
                              void* d_out, int out_size, void* d_ws, size_t ws_size,
                              hipStream_t stream) {
    const float* x = (const float*)d_in[0];
    float* out = (float*)d_out;
    const int rows = in_sizes[0] / N_COLS;
    fill_zero_kernel<<<FILL_BLOCKS, TPB, 0, stream>>>((float4*)out);
    topk_select_kernel<<<rows, TPB, 0, stream>>>(x, out);
}